// Round 1
// baseline (2521.512 us; speedup 1.0000x reference)
//
#include <hip/hip_runtime.h>
#include <cstddef>

#define N_NODES 30000
#define N_EDGES 480000
#define RP_STRIDE 30016   // padded rowptr stride (N_NODES+1 rounded up)

__device__ __forceinline__ float bcast(float v, int l) {
  return __int_as_float(__builtin_amdgcn_readlane(__float_as_int(v), l));
}

// ---------------------------------------------------------------- rowptr ----
// rp[a][r] = lower_bound(rows_a, r); rows are sorted. 4 adjacencies at once.
__global__ __launch_bounds__(256) void build_rowptr_kernel(
    const int* __restrict__ r0, const int* __restrict__ r1,
    const int* __restrict__ r2, const int* __restrict__ r3,
    int* __restrict__ rp) {
  int t = blockIdx.x * 256 + threadIdx.x;
  int a = t / (N_NODES + 1);
  int r = t - a * (N_NODES + 1);
  if (a >= 4) return;
  const int* rows = (a == 0) ? r0 : (a == 1) ? r1 : (a == 2) ? r2 : r3;
  int lo = 0, hi = N_EDGES;
  while (lo < hi) {
    int mid = (lo + hi) >> 1;
    if (rows[mid] < r) lo = mid + 1; else hi = mid;
  }
  rp[a * RP_STRIDE + r] = lo;
}

// ------------------------------------------------------------------ spmm ----
// out[r][d] = sum_e vals[e]*x[cols[e]][d] over CSR row r. One wave per row,
// lane = d. cols/vals via wave-uniform (scalar) loads; x gathers coalesced.
__global__ __launch_bounds__(256) void spmm_kernel(
    const int* __restrict__ rp, const int* __restrict__ cols,
    const float* __restrict__ vals, const float* __restrict__ x,
    float* __restrict__ out) {
  const int lane = threadIdx.x & 63;
  const int wave = __builtin_amdgcn_readfirstlane((int)(threadIdx.x >> 6));
  const int row = blockIdx.x * 4 + wave;
  if (row >= N_NODES) return;
  const int e0 = rp[row], e1 = rp[row + 1];
  float acc = 0.f;
  int e = e0;
  for (; e + 4 <= e1; e += 4) {
    int c0 = cols[e], c1 = cols[e + 1], c2 = cols[e + 2], c3 = cols[e + 3];
    float v0 = vals[e], v1 = vals[e + 1], v2 = vals[e + 2], v3 = vals[e + 3];
    float x0 = x[(size_t)c0 * 64 + lane];
    float x1 = x[(size_t)c1 * 64 + lane];
    float x2 = x[(size_t)c2 * 64 + lane];
    float x3 = x[(size_t)c3 * 64 + lane];
    acc = fmaf(v0, x0, acc); acc = fmaf(v1, x1, acc);
    acc = fmaf(v2, x2, acc); acc = fmaf(v3, x3, acc);
  }
  for (; e < e1; ++e)
    acc = fmaf(vals[e], x[(size_t)cols[e] * 64 + lane], acc);
  out[(size_t)row * 64 + lane] = acc;
}

// -------------------------------------------------------------- enc GEMM ----
// Z[M][64] = F[M][K] @ W[K][64]. Wave owns 8 rows (uniform -> F via s_load),
// lane owns one output col; W chunk staged in LDS, 1 ds_read serves 8 fmacs.
template <int K>
__global__ __launch_bounds__(256) void gemm_enc_kernel(
    const float* __restrict__ F, const float* __restrict__ W,
    float* __restrict__ Z, int M) {
  constexpr int KC = 40;  // divides 3000 and 1000
  __shared__ __attribute__((aligned(16))) float Wl[KC * 64];
  const int tid = threadIdx.x;
  const int lane = tid & 63;
  const int wave = __builtin_amdgcn_readfirstlane(tid >> 6);
  const int rowBase = blockIdx.x * 32 + wave * 8;
  const float* Fr[8];
  bool valid[8];
#pragma unroll
  for (int i = 0; i < 8; ++i) {
    int r = rowBase + i;
    valid[i] = r < M;
    Fr[i] = F + (size_t)(valid[i] ? r : M - 1) * K;
  }
  float acc[8] = {0.f, 0.f, 0.f, 0.f, 0.f, 0.f, 0.f, 0.f};
  for (int kb = 0; kb < K; kb += KC) {
    __syncthreads();
#pragma unroll
    for (int j = 0; j < (KC * 64) / (2 * 256); ++j) {  // 5 float2 per thread
      int t2 = tid + j * 256;
      *(float2*)&Wl[t2 * 2] = *(const float2*)&W[(size_t)kb * 64 + t2 * 2];
    }
    __syncthreads();
#pragma unroll 8
    for (int kk = 0; kk < KC; ++kk) {
      float w = Wl[kk * 64 + lane];
#pragma unroll
      for (int i = 0; i < 8; ++i)
        acc[i] = fmaf(Fr[i][kb + kk], w, acc[i]);
    }
  }
#pragma unroll
  for (int i = 0; i < 8; ++i)
    if (valid[i]) Z[(size_t)(rowBase + i) * 64 + lane] = acc[i];
}

// -------------------------------------------------------------- dec GEMM ----
// Out[M][NC] = T[M][64] @ Wd[64][NC]. Same structure; loop over 64-col chunks.
template <int NC>
__global__ __launch_bounds__(256) void gemm_dec_kernel(
    const float* __restrict__ T, const float* __restrict__ Wd,
    float* __restrict__ Out, int M) {
  __shared__ __attribute__((aligned(16))) float Wl[64 * 64];
  const int tid = threadIdx.x;
  const int lane = tid & 63;
  const int wave = __builtin_amdgcn_readfirstlane(tid >> 6);
  const int rowBase = blockIdx.x * 32 + wave * 8;
  const float* Tr[8];
  bool valid[8];
#pragma unroll
  for (int i = 0; i < 8; ++i) {
    int r = rowBase + i;
    valid[i] = r < M;
    Tr[i] = T + (size_t)(valid[i] ? r : M - 1) * 64;
  }
  for (int cc = 0; cc < NC; cc += 64) {
    const int cw = (NC - cc < 64) ? (NC - cc) : 64;
    __syncthreads();
    if (cw == 64) {
#pragma unroll
      for (int j = 0; j < 4; ++j) {
        int q = tid + j * 256;              // q in [0,1024)
        int k = q >> 4, t4 = (q & 15) * 4;
        *(float4*)&Wl[k * 64 + t4] = *(const float4*)&Wd[(size_t)k * NC + cc + t4];
      }
    } else {
      for (int q = tid; q < 64 * 64; q += 256) {
        int k = q >> 6, t = q & 63;
        if (t < cw) Wl[q] = Wd[(size_t)k * NC + cc + t];
      }
    }
    __syncthreads();
    float acc[8] = {0.f, 0.f, 0.f, 0.f, 0.f, 0.f, 0.f, 0.f};
#pragma unroll 8
    for (int k = 0; k < 64; ++k) {
      float w = Wl[k * 64 + lane];
#pragma unroll
      for (int i = 0; i < 8; ++i)
        acc[i] = fmaf(Tr[i][k], w, acc[i]);
    }
    if (lane < cw) {
#pragma unroll
      for (int i = 0; i < 8; ++i)
        if (valid[i]) Out[(size_t)(rowBase + i) * NC + cc + lane] = acc[i];
    }
  }
}

// ------------------------------------------------------------- attention ----
// Per node: v_k = tanh(e_k@W); s_k = v_k . u; alpha = softmax(s); out = sum.
// Wave owns 4 nodes; lane = output dim; broadcasts via v_readlane.
__global__ __launch_bounds__(256) void attention_kernel(
    const float* __restrict__ E1, const float* __restrict__ E2,
    const float* __restrict__ W, const float* __restrict__ U,
    float* __restrict__ Out) {
  __shared__ __attribute__((aligned(16))) float Wl[64 * 64];
  __shared__ float Ul[64];
  const int tid = threadIdx.x;
  const int lane = tid & 63;
#pragma unroll
  for (int j = 0; j < 4; ++j) {
    int t = tid * 4 + j * 1024;
    *(float4*)&Wl[t] = *(const float4*)&W[t];
  }
  if (tid < 64) Ul[tid] = U[tid];
  __syncthreads();
  const int wave = __builtin_amdgcn_readfirstlane(tid >> 6);
  const int row0 = (blockIdx.x * 4 + wave) * 4;
  if (row0 >= N_NODES) return;
  float e1[4], e2[4];
#pragma unroll
  for (int i = 0; i < 4; ++i) {
    e1[i] = E1[(size_t)(row0 + i) * 64 + lane];
    e2[i] = E2[(size_t)(row0 + i) * 64 + lane];
  }
  float v1[4] = {0.f, 0.f, 0.f, 0.f}, v2[4] = {0.f, 0.f, 0.f, 0.f};
#pragma unroll
  for (int k = 0; k < 64; ++k) {
    float w = Wl[k * 64 + lane];
#pragma unroll
    for (int i = 0; i < 4; ++i) {
      v1[i] = fmaf(bcast(e1[i], k), w, v1[i]);
      v2[i] = fmaf(bcast(e2[i], k), w, v2[i]);
    }
  }
  float u = Ul[lane];
#pragma unroll
  for (int i = 0; i < 4; ++i) {
    float p1 = tanhf(v1[i]) * u, p2 = tanhf(v2[i]) * u;
#pragma unroll
    for (int m = 32; m; m >>= 1) {
      p1 += __shfl_xor(p1, m);
      p2 += __shfl_xor(p2, m);
    }
    float mx = fmaxf(p1, p2);
    float a1 = expf(p1 - mx), a2 = expf(p2 - mx);
    float inv = 1.f / (a1 + a2);
    Out[(size_t)(row0 + i) * 64 + lane] = (a1 * e1[i] + a2 * e2[i]) * inv;
  }
}

// ------------------------------------------------------------------- MLP ----
// 3-layer MLP fused; wave owns 8 rows. Layer1 input via s_load (uniform rows);
// layers 2/3 broadcast hidden activations via v_readlane (VALU, not LDS).
template <int DOUT, bool SIG>
__global__ __launch_bounds__(256) void mlp_kernel(
    const float* __restrict__ X,
    const float* __restrict__ W1, const float* __restrict__ B1,
    const float* __restrict__ W2, const float* __restrict__ B2,
    const float* __restrict__ W3, const float* __restrict__ B3,
    float* __restrict__ Out) {
  __shared__ __attribute__((aligned(16))) float W1l[64 * 128];
  __shared__ __attribute__((aligned(16))) float W2l[128 * 64];
  __shared__ __attribute__((aligned(16))) float W3l[64 * DOUT];
  __shared__ float B1l[128], B2l[64], B3l[DOUT];
  const int tid = threadIdx.x;
  const int lane = tid & 63;
#pragma unroll
  for (int j = 0; j < 8; ++j) {
    int t = tid * 4 + j * 1024;
    *(float4*)&W1l[t] = *(const float4*)&W1[t];
    *(float4*)&W2l[t] = *(const float4*)&W2[t];
  }
  for (int t = tid * 4; t < 64 * DOUT; t += 1024)
    *(float4*)&W3l[t] = *(const float4*)&W3[t];
  if (tid < 128) B1l[tid] = B1[tid];
  if (tid < 64) B2l[tid] = B2[tid];
  if (tid < DOUT) B3l[tid] = B3[tid];
  __syncthreads();
  const int wave = __builtin_amdgcn_readfirstlane(tid >> 6);
  const int row0 = blockIdx.x * 32 + wave * 8;
  const float* Xr[8];
  bool valid[8];
#pragma unroll
  for (int i = 0; i < 8; ++i) {
    int r = row0 + i;
    valid[i] = r < N_NODES;
    Xr[i] = X + (size_t)(valid[i] ? r : N_NODES - 1) * 64;
  }
  // layer 1: 64 -> 128 (lane covers col lane and lane+64)
  float hA[8], hB[8];
#pragma unroll
  for (int i = 0; i < 8; ++i) { hA[i] = B1l[lane]; hB[i] = B1l[64 + lane]; }
#pragma unroll 8
  for (int k = 0; k < 64; ++k) {
    float w0 = W1l[k * 128 + lane], w1 = W1l[k * 128 + 64 + lane];
#pragma unroll
    for (int i = 0; i < 8; ++i) {
      float xv = Xr[i][k];
      hA[i] = fmaf(xv, w0, hA[i]);
      hB[i] = fmaf(xv, w1, hB[i]);
    }
  }
#pragma unroll
  for (int i = 0; i < 8; ++i) {
    hA[i] = fmaxf(hA[i], 0.f);
    hB[i] = fmaxf(hB[i], 0.f);
  }
  // layer 2: 128 -> 64
  float h2[8];
#pragma unroll
  for (int i = 0; i < 8; ++i) h2[i] = B2l[lane];
#pragma unroll
  for (int k = 0; k < 64; ++k) {
    float w = W2l[k * 64 + lane];
#pragma unroll
    for (int i = 0; i < 8; ++i) h2[i] = fmaf(bcast(hA[i], k), w, h2[i]);
  }
#pragma unroll
  for (int k = 0; k < 64; ++k) {
    float w = W2l[(k + 64) * 64 + lane];
#pragma unroll
    for (int i = 0; i < 8; ++i) h2[i] = fmaf(bcast(hB[i], k), w, h2[i]);
  }
#pragma unroll
  for (int i = 0; i < 8; ++i) h2[i] = fmaxf(h2[i], 0.f);
  // layer 3
  if constexpr (DOUT == 64) {
    float o[8];
#pragma unroll
    for (int i = 0; i < 8; ++i) o[i] = B3l[lane];
#pragma unroll
    for (int k = 0; k < 64; ++k) {
      float w = W3l[k * 64 + lane];
#pragma unroll
      for (int i = 0; i < 8; ++i) o[i] = fmaf(bcast(h2[i], k), w, o[i]);
    }
#pragma unroll
    for (int i = 0; i < 8; ++i)
      if (valid[i]) Out[(size_t)(row0 + i) * 64 + lane] = o[i];
  } else {  // DOUT == 1 : dot with w3 column, reduce, (sigmoid), store
    float w3 = W3l[lane];
#pragma unroll
    for (int i = 0; i < 8; ++i) {
      float t = h2[i] * w3;
#pragma unroll
      for (int m = 32; m; m >>= 1) t += __shfl_xor(t, m);
      float o = t + B3l[0];
      if (SIG) o = 1.f / (1.f + expf(-o));
      if (lane == 0 && valid[i]) Out[row0 + i] = o;
    }
  }
}

// ---------------------------------------------------------------- launch ----
extern "C" void kernel_launch(void* const* d_in, const int* in_sizes, int n_in,
                              void* d_out, int out_size, void* d_ws, size_t ws_size,
                              hipStream_t stream) {
  const float* F1 = (const float*)d_in[0];
  const float* F2 = (const float*)d_in[1];
  const int* sp1_r = (const int*)d_in[2];
  const int* sp1_c = (const int*)d_in[3];
  const float* sp1_v = (const float*)d_in[4];
  const int* ft1_r = (const int*)d_in[5];
  const int* ft1_c = (const int*)d_in[6];
  const float* ft1_v = (const float*)d_in[7];
  const int* sp2_r = (const int*)d_in[8];
  const int* sp2_c = (const int*)d_in[9];
  const float* sp2_v = (const float*)d_in[10];
  const int* ft2_r = (const int*)d_in[11];
  const int* ft2_c = (const int*)d_in[12];
  const float* ft2_v = (const float*)d_in[13];
  const float* enc1_w = (const float*)d_in[14];
  const float* enc2_w = (const float*)d_in[15];
  const float* dec1_w = (const float*)d_in[16];
  const float* dec2_w = (const float*)d_in[17];
  const float* att1_w = (const float*)d_in[18];
  const float* att1_u = (const float*)d_in[19];
  const float* att2_w = (const float*)d_in[20];
  const float* att2_u = (const float*)d_in[21];
  const float* attc_w = (const float*)d_in[22];
  const float* attc_u = (const float*)d_in[23];
  const float* const* P = (const float* const*)d_in;  // convenience for MLP params

  float* out = (float*)d_out;
  int* rp = (int*)d_ws;                       // 4 * RP_STRIDE ints
  float* fws = (float*)d_ws + 4 * RP_STRIDE;  // float scratch
  const size_t NE = (size_t)N_NODES * 64;     // 1,920,000
  float* z1 = fws;
  float* z2 = z1 + NE;
  float* esp1 = z2 + NE;
  float* eft1 = esp1 + NE;
  float* esp2 = eft1 + NE;
  float* eft2 = esp2 + NE;
  float* tmp1 = z1;  // reuse after z no longer needed
  float* tmp2 = z2;

  float* o_emb1 = out;
  float* o_emb2 = out + NE;
  float* o_12 = out + 2 * NE;
  float* o_21 = out + 3 * NE;
  float* o_p1 = out + 4 * NE;
  float* o_p2 = out + 4 * NE + N_NODES;
  float* o_embc = out + 4 * NE + 2 * N_NODES;
  float* o_rec1 = o_embc + NE;                       // 30000*3000
  float* o_rec2 = o_rec1 + (size_t)N_NODES * 3000;   // 30000*1000

  dim3 blk(256);
  // row pointers for the 4 adjacencies
  build_rowptr_kernel<<<dim3((4 * (N_NODES + 1) + 255) / 256), blk, 0, stream>>>(
      sp1_r, ft1_r, sp2_r, ft2_r, rp);
  // encoders
  gemm_enc_kernel<3000><<<dim3(938), blk, 0, stream>>>(F1, enc1_w, z1, N_NODES);
  gemm_enc_kernel<1000><<<dim3(938), blk, 0, stream>>>(F2, enc2_w, z2, N_NODES);
  // 4 spmms
  spmm_kernel<<<dim3(7500), blk, 0, stream>>>(rp + 0 * RP_STRIDE, sp1_c, sp1_v, z1, esp1);
  spmm_kernel<<<dim3(7500), blk, 0, stream>>>(rp + 1 * RP_STRIDE, ft1_c, ft1_v, z1, eft1);
  spmm_kernel<<<dim3(7500), blk, 0, stream>>>(rp + 2 * RP_STRIDE, sp2_c, sp2_v, z2, esp2);
  spmm_kernel<<<dim3(7500), blk, 0, stream>>>(rp + 3 * RP_STRIDE, ft2_c, ft2_v, z2, eft2);
  // within-modality attention
  attention_kernel<<<dim3(1875), blk, 0, stream>>>(esp1, eft1, att1_w, att1_u, o_emb1);
  attention_kernel<<<dim3(1875), blk, 0, stream>>>(esp2, eft2, att2_w, att2_u, o_emb2);
  // MLP heads (t12: in 24..29, t21: 30..35, d1: 36..41, d2: 42..47)
  mlp_kernel<64, false><<<dim3(938), blk, 0, stream>>>(
      o_emb1, P[24], P[25], P[26], P[27], P[28], P[29], o_12);
  mlp_kernel<64, false><<<dim3(938), blk, 0, stream>>>(
      o_emb2, P[30], P[31], P[32], P[33], P[34], P[35], o_21);
  mlp_kernel<1, true><<<dim3(938), blk, 0, stream>>>(
      o_emb1, P[36], P[37], P[38], P[39], P[40], P[41], o_p1);
  mlp_kernel<1, true><<<dim3(938), blk, 0, stream>>>(
      o_emb2, P[42], P[43], P[44], P[45], P[46], P[47], o_p2);
  // cross-modality attention
  attention_kernel<<<dim3(1875), blk, 0, stream>>>(o_emb1, o_emb2, attc_w, attc_u, o_embc);
  // recon: spmm first (A@(X@W) == (A@X)@W), then dense [30000,64]@[64,NC]
  spmm_kernel<<<dim3(7500), blk, 0, stream>>>(rp + 0 * RP_STRIDE, sp1_c, sp1_v, o_embc, tmp1);
  spmm_kernel<<<dim3(7500), blk, 0, stream>>>(rp + 2 * RP_STRIDE, sp2_c, sp2_v, o_embc, tmp2);
  gemm_dec_kernel<3000><<<dim3(938), blk, 0, stream>>>(tmp1, dec1_w, o_rec1, N_NODES);
  gemm_dec_kernel<1000><<<dim3(938), blk, 0, stream>>>(tmp2, dec2_w, o_rec2, N_NODES);
}

// Round 3
// 1929.572 us; speedup vs baseline: 1.3068x; 1.3068x over previous
//
#include <hip/hip_runtime.h>
#include <cstddef>

#define N_NODES 30000
#define N_EDGES 480000
#define RP_STRIDE 30016   // padded rowptr stride (N_NODES+1 rounded up)

__device__ __forceinline__ float bcast(float v, int l) {
  return __int_as_float(__builtin_amdgcn_readlane(__float_as_int(v), l));
}

// ---------------------------------------------------------------- rowptr ----
// rp[a][r] = lower_bound(rows_a, r); rows are sorted. 4 adjacencies at once.
__global__ __launch_bounds__(256) void build_rowptr_kernel(
    const int* __restrict__ r0, const int* __restrict__ r1,
    const int* __restrict__ r2, const int* __restrict__ r3,
    int* __restrict__ rp) {
  int t = blockIdx.x * 256 + threadIdx.x;
  int a = t / (N_NODES + 1);
  int r = t - a * (N_NODES + 1);
  if (a >= 4) return;
  const int* rows = (a == 0) ? r0 : (a == 1) ? r1 : (a == 2) ? r2 : r3;
  int lo = 0, hi = N_EDGES;
  while (lo < hi) {
    int mid = (lo + hi) >> 1;
    if (rows[mid] < r) lo = mid + 1; else hi = mid;
  }
  rp[a * RP_STRIDE + r] = lo;
}

// ------------------------------------------------------------------ spmm ----
// out[r][d] = sum_e vals[e]*x[cols[e]][d] over CSR row r. One wave per row,
// lane = d. cols/vals via wave-uniform (scalar) loads; x gathers coalesced.
__global__ __launch_bounds__(256) void spmm_kernel(
    const int* __restrict__ rp, const int* __restrict__ cols,
    const float* __restrict__ vals, const float* __restrict__ x,
    float* __restrict__ out) {
  const int lane = threadIdx.x & 63;
  const int wave = __builtin_amdgcn_readfirstlane((int)(threadIdx.x >> 6));
  const int row = blockIdx.x * 4 + wave;
  if (row >= N_NODES) return;
  const int e0 = rp[row], e1 = rp[row + 1];
  float acc = 0.f;
  int e = e0;
  for (; e + 4 <= e1; e += 4) {
    int c0 = cols[e], c1 = cols[e + 1], c2 = cols[e + 2], c3 = cols[e + 3];
    float v0 = vals[e], v1 = vals[e + 1], v2 = vals[e + 2], v3 = vals[e + 3];
    float x0 = x[(size_t)c0 * 64 + lane];
    float x1 = x[(size_t)c1 * 64 + lane];
    float x2 = x[(size_t)c2 * 64 + lane];
    float x3 = x[(size_t)c3 * 64 + lane];
    acc = fmaf(v0, x0, acc); acc = fmaf(v1, x1, acc);
    acc = fmaf(v2, x2, acc); acc = fmaf(v3, x3, acc);
  }
  for (; e < e1; ++e)
    acc = fmaf(vals[e], x[(size_t)cols[e] * 64 + lane], acc);
  out[(size_t)row * 64 + lane] = acc;
}

// -------------------------------------------------------------- enc GEMM ----
// Z[M][64] = F[M][K] @ W[K][64]. LDS-tiled: block = 64 rows x 64 cols,
// K-chunks of 64. Coalesced float4 staging; lane computes 2 rows x 8 cols.
// LDS stride 68 floats (272B, 16B-aligned; reads <=2-way conflict = free).
template <int K>
__global__ __launch_bounds__(256) void gemm_enc_kernel(
    const float* __restrict__ F, const float* __restrict__ W,
    float* __restrict__ Z, int M) {
  constexpr int KC = 64;
  constexpr int LDF = 68;
  __shared__ __attribute__((aligned(16))) float Fl[64 * LDF];
  __shared__ __attribute__((aligned(16))) float Wl[64 * LDF];
  const int tid = threadIdx.x;
  const int lane = tid & 63;
  const int lr = lane >> 3;       // 0..7
  const int lc = lane & 7;        // 0..7
  const int wave = tid >> 6;      // 0..3
  const int row0 = blockIdx.x * 64;
  const int r_a = wave * 16 + lr * 2;   // lane's first row within tile
  const int srow = tid >> 4;            // staging: row/k 0..15 (+j*16)
  const int sk4 = (tid & 15) * 4;       // staging: float4 slot
  float acc[2][8] = {};
  for (int kb = 0; kb < K; kb += KC) {
    __syncthreads();
    // stage F tile (64 rows x 64 k), zero-pad K tail
#pragma unroll
    for (int j = 0; j < 4; ++j) {
      int r = srow + j * 16;
      int gr = row0 + r; if (gr >= M) gr = M - 1;
      float4 v;
      if (kb + sk4 + 3 < K) {
        v = *(const float4*)&F[(size_t)gr * K + kb + sk4];
      } else {
        float t0 = (kb + sk4 + 0 < K) ? F[(size_t)gr * K + kb + sk4 + 0] : 0.f;
        float t1 = (kb + sk4 + 1 < K) ? F[(size_t)gr * K + kb + sk4 + 1] : 0.f;
        float t2 = (kb + sk4 + 2 < K) ? F[(size_t)gr * K + kb + sk4 + 2] : 0.f;
        float t3 = (kb + sk4 + 3 < K) ? F[(size_t)gr * K + kb + sk4 + 3] : 0.f;
        v = make_float4(t0, t1, t2, t3);
      }
      *(float4*)&Fl[r * LDF + sk4] = v;
    }
    // stage W chunk (64 k x 64 cols), zero-pad K tail
#pragma unroll
    for (int j = 0; j < 4; ++j) {
      int kk = srow + j * 16;
      float4 v = make_float4(0.f, 0.f, 0.f, 0.f);
      if (kb + kk < K) v = *(const float4*)&W[(size_t)(kb + kk) * 64 + sk4];
      *(float4*)&Wl[kk * LDF + sk4] = v;
    }
    __syncthreads();
#pragma unroll 8
    for (int kk = 0; kk < KC; ++kk) {
      float f0 = Fl[(r_a + 0) * LDF + kk];
      float f1 = Fl[(r_a + 1) * LDF + kk];
      float4 wA = *(const float4*)&Wl[kk * LDF + lc * 8];
      float4 wB = *(const float4*)&Wl[kk * LDF + lc * 8 + 4];
      float w[8] = {wA.x, wA.y, wA.z, wA.w, wB.x, wB.y, wB.z, wB.w};
#pragma unroll
      for (int q = 0; q < 8; ++q) {
        acc[0][q] = fmaf(f0, w[q], acc[0][q]);
        acc[1][q] = fmaf(f1, w[q], acc[1][q]);
      }
    }
  }
#pragma unroll
  for (int i = 0; i < 2; ++i) {
    int r = row0 + r_a + i;
    if (r < M) {
      *(float4*)&Z[(size_t)r * 64 + lc * 8] =
          make_float4(acc[i][0], acc[i][1], acc[i][2], acc[i][3]);
      *(float4*)&Z[(size_t)r * 64 + lc * 8 + 4] =
          make_float4(acc[i][4], acc[i][5], acc[i][6], acc[i][7]);
    }
  }
}

// -------------------------------------------------------------- dec GEMM ----
// Out[M][NC] = T[M][64] @ Wd[64][NC]. T tile staged once (16KB); W staged per
// 64-col chunk. Same 2x8 lane tile as enc.
template <int NC>
__global__ __launch_bounds__(256) void gemm_dec_kernel(
    const float* __restrict__ T, const float* __restrict__ Wd,
    float* __restrict__ Out, int M) {
  constexpr int LDF = 68;
  __shared__ __attribute__((aligned(16))) float Tl[64 * LDF];
  __shared__ __attribute__((aligned(16))) float Wl[64 * LDF];
  const int tid = threadIdx.x;
  const int lane = tid & 63;
  const int lr = lane >> 3;
  const int lc = lane & 7;
  const int wave = tid >> 6;
  const int row0 = blockIdx.x * 64;
  const int r_a = wave * 16 + lr * 2;
  const int srow = tid >> 4;
  const int sk4 = (tid & 15) * 4;
  // stage T tile once: 64 rows x 64 k
#pragma unroll
  for (int j = 0; j < 4; ++j) {
    int r = srow + j * 16;
    int gr = row0 + r; if (gr >= M) gr = M - 1;
    *(float4*)&Tl[r * LDF + sk4] = *(const float4*)&T[(size_t)gr * 64 + sk4];
  }
  for (int cc = 0; cc < NC; cc += 64) {
    __syncthreads();  // Wl safe to overwrite (and Tl visible on first iter)
    // stage W chunk (64 k x <=64 cols), zero-pad col tail
#pragma unroll
    for (int j = 0; j < 4; ++j) {
      int k = srow + j * 16;
      float4 v;
      if (cc + sk4 + 3 < NC) {
        v = *(const float4*)&Wd[(size_t)k * NC + cc + sk4];
      } else {
        float t0 = (cc + sk4 + 0 < NC) ? Wd[(size_t)k * NC + cc + sk4 + 0] : 0.f;
        float t1 = (cc + sk4 + 1 < NC) ? Wd[(size_t)k * NC + cc + sk4 + 1] : 0.f;
        float t2 = (cc + sk4 + 2 < NC) ? Wd[(size_t)k * NC + cc + sk4 + 2] : 0.f;
        float t3 = (cc + sk4 + 3 < NC) ? Wd[(size_t)k * NC + cc + sk4 + 3] : 0.f;
        v = make_float4(t0, t1, t2, t3);
      }
      *(float4*)&Wl[k * LDF + sk4] = v;
    }
    __syncthreads();
    float acc[2][8] = {};
#pragma unroll 8
    for (int kk = 0; kk < 64; ++kk) {
      float f0 = Tl[(r_a + 0) * LDF + kk];
      float f1 = Tl[(r_a + 1) * LDF + kk];
      float4 wA = *(const float4*)&Wl[kk * LDF + lc * 8];
      float4 wB = *(const float4*)&Wl[kk * LDF + lc * 8 + 4];
      float w[8] = {wA.x, wA.y, wA.z, wA.w, wB.x, wB.y, wB.z, wB.w};
#pragma unroll
      for (int q = 0; q < 8; ++q) {
        acc[0][q] = fmaf(f0, w[q], acc[0][q]);
        acc[1][q] = fmaf(f1, w[q], acc[1][q]);
      }
    }
#pragma unroll
    for (int i = 0; i < 2; ++i) {
      int r = row0 + r_a + i;
      if (r < M) {
        if (cc + 64 <= NC) {
          *(float4*)&Out[(size_t)r * NC + cc + lc * 8] =
              make_float4(acc[i][0], acc[i][1], acc[i][2], acc[i][3]);
          *(float4*)&Out[(size_t)r * NC + cc + lc * 8 + 4] =
              make_float4(acc[i][4], acc[i][5], acc[i][6], acc[i][7]);
        } else {
#pragma unroll
          for (int q = 0; q < 8; ++q) {
            int c = cc + lc * 8 + q;
            if (c < NC) Out[(size_t)r * NC + c] = acc[i][q];
          }
        }
      }
    }
  }
}

// ------------------------------------------------------------- attention ----
// Per node: v_k = tanh(e_k@W); s_k = v_k . u; alpha = softmax(s); out = sum.
// Wave owns 4 nodes; lane = output dim; broadcasts via v_readlane.
__global__ __launch_bounds__(256) void attention_kernel(
    const float* __restrict__ E1, const float* __restrict__ E2,
    const float* __restrict__ W, const float* __restrict__ U,
    float* __restrict__ Out) {
  __shared__ __attribute__((aligned(16))) float Wl[64 * 64];
  __shared__ float Ul[64];
  const int tid = threadIdx.x;
  const int lane = tid & 63;
#pragma unroll
  for (int j = 0; j < 4; ++j) {
    int t = tid * 4 + j * 1024;
    *(float4*)&Wl[t] = *(const float4*)&W[t];
  }
  if (tid < 64) Ul[tid] = U[tid];
  __syncthreads();
  const int wave = __builtin_amdgcn_readfirstlane(tid >> 6);
  const int row0 = (blockIdx.x * 4 + wave) * 4;
  if (row0 >= N_NODES) return;
  float e1[4], e2[4];
#pragma unroll
  for (int i = 0; i < 4; ++i) {
    e1[i] = E1[(size_t)(row0 + i) * 64 + lane];
    e2[i] = E2[(size_t)(row0 + i) * 64 + lane];
  }
  float v1[4] = {0.f, 0.f, 0.f, 0.f}, v2[4] = {0.f, 0.f, 0.f, 0.f};
#pragma unroll
  for (int k = 0; k < 64; ++k) {
    float w = Wl[k * 64 + lane];
#pragma unroll
    for (int i = 0; i < 4; ++i) {
      v1[i] = fmaf(bcast(e1[i], k), w, v1[i]);
      v2[i] = fmaf(bcast(e2[i], k), w, v2[i]);
    }
  }
  float u = Ul[lane];
#pragma unroll
  for (int i = 0; i < 4; ++i) {
    float p1 = tanhf(v1[i]) * u, p2 = tanhf(v2[i]) * u;
#pragma unroll
    for (int m = 32; m; m >>= 1) {
      p1 += __shfl_xor(p1, m);
      p2 += __shfl_xor(p2, m);
    }
    float mx = fmaxf(p1, p2);
    float a1 = expf(p1 - mx), a2 = expf(p2 - mx);
    float inv = 1.f / (a1 + a2);
    Out[(size_t)(row0 + i) * 64 + lane] = (a1 * e1[i] + a2 * e2[i]) * inv;
  }
}

// ------------------------------------------------------------------- MLP ----
// 3-layer MLP fused; wave owns 8 rows. All layers use coalesced per-lane row
// loads + v_readlane broadcast (VALU), avoiding scalar-load latency chains.
template <int DOUT, bool SIG>
__global__ __launch_bounds__(256) void mlp_kernel(
    const float* __restrict__ X,
    const float* __restrict__ W1, const float* __restrict__ B1,
    const float* __restrict__ W2, const float* __restrict__ B2,
    const float* __restrict__ W3, const float* __restrict__ B3,
    float* __restrict__ Out) {
  __shared__ __attribute__((aligned(16))) float W1l[64 * 128];
  __shared__ __attribute__((aligned(16))) float W2l[128 * 64];
  __shared__ __attribute__((aligned(16))) float W3l[64 * DOUT];
  __shared__ float B1l[128], B2l[64], B3l[DOUT];
  const int tid = threadIdx.x;
  const int lane = tid & 63;
#pragma unroll
  for (int j = 0; j < 8; ++j) {
    int t = tid * 4 + j * 1024;
    *(float4*)&W1l[t] = *(const float4*)&W1[t];
    *(float4*)&W2l[t] = *(const float4*)&W2[t];
  }
  for (int t = tid * 4; t < 64 * DOUT; t += 1024)
    *(float4*)&W3l[t] = *(const float4*)&W3[t];
  if (tid < 128) B1l[tid] = B1[tid];
  if (tid < 64) B2l[tid] = B2[tid];
  if (tid < DOUT) B3l[tid] = B3[tid];
  __syncthreads();
  const int wave = __builtin_amdgcn_readfirstlane(tid >> 6);
  const int row0 = blockIdx.x * 32 + wave * 8;
  // coalesced load of the 8 input rows: lane = feature dim
  float x[8];
  bool valid[8];
#pragma unroll
  for (int i = 0; i < 8; ++i) {
    int r = row0 + i;
    valid[i] = r < N_NODES;
    x[i] = X[(size_t)(valid[i] ? r : N_NODES - 1) * 64 + lane];
  }
  // layer 1: 64 -> 128 (lane covers col lane and lane+64); broadcast x via readlane
  float hA[8], hB[8];
#pragma unroll
  for (int i = 0; i < 8; ++i) { hA[i] = B1l[lane]; hB[i] = B1l[64 + lane]; }
#pragma unroll 8
  for (int k = 0; k < 64; ++k) {
    float w0 = W1l[k * 128 + lane], w1 = W1l[k * 128 + 64 + lane];
#pragma unroll
    for (int i = 0; i < 8; ++i) {
      float xv = bcast(x[i], k);
      hA[i] = fmaf(xv, w0, hA[i]);
      hB[i] = fmaf(xv, w1, hB[i]);
    }
  }
#pragma unroll
  for (int i = 0; i < 8; ++i) {
    hA[i] = fmaxf(hA[i], 0.f);
    hB[i] = fmaxf(hB[i], 0.f);
  }
  // layer 2: 128 -> 64
  float h2[8];
#pragma unroll
  for (int i = 0; i < 8; ++i) h2[i] = B2l[lane];
#pragma unroll
  for (int k = 0; k < 64; ++k) {
    float w = W2l[k * 64 + lane];
#pragma unroll
    for (int i = 0; i < 8; ++i) h2[i] = fmaf(bcast(hA[i], k), w, h2[i]);
  }
#pragma unroll
  for (int k = 0; k < 64; ++k) {
    float w = W2l[(k + 64) * 64 + lane];
#pragma unroll
    for (int i = 0; i < 8; ++i) h2[i] = fmaf(bcast(hB[i], k), w, h2[i]);
  }
#pragma unroll
  for (int i = 0; i < 8; ++i) h2[i] = fmaxf(h2[i], 0.f);
  // layer 3
  if constexpr (DOUT == 64) {
    float o[8];
#pragma unroll
    for (int i = 0; i < 8; ++i) o[i] = B3l[lane];
#pragma unroll
    for (int k = 0; k < 64; ++k) {
      float w = W3l[k * 64 + lane];
#pragma unroll
      for (int i = 0; i < 8; ++i) o[i] = fmaf(bcast(h2[i], k), w, o[i]);
    }
#pragma unroll
    for (int i = 0; i < 8; ++i)
      if (valid[i]) Out[(size_t)(row0 + i) * 64 + lane] = o[i];
  } else {  // DOUT == 1 : dot with w3 column, reduce, (sigmoid), store
    float w3 = W3l[lane];
#pragma unroll
    for (int i = 0; i < 8; ++i) {
      float t = h2[i] * w3;
#pragma unroll
      for (int m = 32; m; m >>= 1) t += __shfl_xor(t, m);
      float o = t + B3l[0];
      if (SIG) o = 1.f / (1.f + expf(-o));
      if (lane == 0 && valid[i]) Out[row0 + i] = o;
    }
  }
}

// ---------------------------------------------------------------- launch ----
extern "C" void kernel_launch(void* const* d_in, const int* in_sizes, int n_in,
                              void* d_out, int out_size, void* d_ws, size_t ws_size,
                              hipStream_t stream) {
  const float* F1 = (const float*)d_in[0];
  const float* F2 = (const float*)d_in[1];
  const int* sp1_r = (const int*)d_in[2];
  const int* sp1_c = (const int*)d_in[3];
  const float* sp1_v = (const float*)d_in[4];
  const int* ft1_r = (const int*)d_in[5];
  const int* ft1_c = (const int*)d_in[6];
  const float* ft1_v = (const float*)d_in[7];
  const int* sp2_r = (const int*)d_in[8];
  const int* sp2_c = (const int*)d_in[9];
  const float* sp2_v = (const float*)d_in[10];
  const int* ft2_r = (const int*)d_in[11];
  const int* ft2_c = (const int*)d_in[12];
  const float* ft2_v = (const float*)d_in[13];
  const float* enc1_w = (const float*)d_in[14];
  const float* enc2_w = (const float*)d_in[15];
  const float* dec1_w = (const float*)d_in[16];
  const float* dec2_w = (const float*)d_in[17];
  const float* att1_w = (const float*)d_in[18];
  const float* att1_u = (const float*)d_in[19];
  const float* att2_w = (const float*)d_in[20];
  const float* att2_u = (const float*)d_in[21];
  const float* attc_w = (const float*)d_in[22];
  const float* attc_u = (const float*)d_in[23];
  const float* const* P = (const float* const*)d_in;  // convenience for MLP params

  float* out = (float*)d_out;
  int* rp = (int*)d_ws;                       // 4 * RP_STRIDE ints
  float* fws = (float*)d_ws + 4 * RP_STRIDE;  // float scratch
  const size_t NE = (size_t)N_NODES * 64;     // 1,920,000
  float* z1 = fws;
  float* z2 = z1 + NE;
  float* esp1 = z2 + NE;
  float* eft1 = esp1 + NE;
  float* esp2 = eft1 + NE;
  float* eft2 = esp2 + NE;
  float* tmp1 = z1;  // reuse after z no longer needed
  float* tmp2 = z2;

  float* o_emb1 = out;
  float* o_emb2 = out + NE;
  float* o_12 = out + 2 * NE;
  float* o_21 = out + 3 * NE;
  float* o_p1 = out + 4 * NE;
  float* o_p2 = out + 4 * NE + N_NODES;
  float* o_embc = out + 4 * NE + 2 * N_NODES;
  float* o_rec1 = o_embc + NE;                       // 30000*3000
  float* o_rec2 = o_rec1 + (size_t)N_NODES * 3000;   // 30000*1000

  dim3 blk(256);
  const int gemm_grid = (N_NODES + 63) / 64;  // 469
  // row pointers for the 4 adjacencies
  build_rowptr_kernel<<<dim3((4 * (N_NODES + 1) + 255) / 256), blk, 0, stream>>>(
      sp1_r, ft1_r, sp2_r, ft2_r, rp);
  // encoders
  gemm_enc_kernel<3000><<<dim3(gemm_grid), blk, 0, stream>>>(F1, enc1_w, z1, N_NODES);
  gemm_enc_kernel<1000><<<dim3(gemm_grid), blk, 0, stream>>>(F2, enc2_w, z2, N_NODES);
  // 4 spmms
  spmm_kernel<<<dim3(7500), blk, 0, stream>>>(rp + 0 * RP_STRIDE, sp1_c, sp1_v, z1, esp1);
  spmm_kernel<<<dim3(7500), blk, 0, stream>>>(rp + 1 * RP_STRIDE, ft1_c, ft1_v, z1, eft1);
  spmm_kernel<<<dim3(7500), blk, 0, stream>>>(rp + 2 * RP_STRIDE, sp2_c, sp2_v, z2, esp2);
  spmm_kernel<<<dim3(7500), blk, 0, stream>>>(rp + 3 * RP_STRIDE, ft2_c, ft2_v, z2, eft2);
  // within-modality attention
  attention_kernel<<<dim3(1875), blk, 0, stream>>>(esp1, eft1, att1_w, att1_u, o_emb1);
  attention_kernel<<<dim3(1875), blk, 0, stream>>>(esp2, eft2, att2_w, att2_u, o_emb2);
  // MLP heads (t12: in 24..29, t21: 30..35, d1: 36..41, d2: 42..47)
  mlp_kernel<64, false><<<dim3(938), blk, 0, stream>>>(
      o_emb1, P[24], P[25], P[26], P[27], P[28], P[29], o_12);
  mlp_kernel<64, false><<<dim3(938), blk, 0, stream>>>(
      o_emb2, P[30], P[31], P[32], P[33], P[34], P[35], o_21);
  mlp_kernel<1, true><<<dim3(938), blk, 0, stream>>>(
      o_emb1, P[36], P[37], P[38], P[39], P[40], P[41], o_p1);
  mlp_kernel<1, true><<<dim3(938), blk, 0, stream>>>(
      o_emb2, P[42], P[43], P[44], P[45], P[46], P[47], o_p2);
  // cross-modality attention
  attention_kernel<<<dim3(1875), blk, 0, stream>>>(o_emb1, o_emb2, attc_w, attc_u, o_embc);
  // recon: spmm first (A@(X@W) == (A@X)@W), then dense [30000,64]@[64,NC]
  spmm_kernel<<<dim3(7500), blk, 0, stream>>>(rp + 0 * RP_STRIDE, sp1_c, sp1_v, o_embc, tmp1);
  spmm_kernel<<<dim3(7500), blk, 0, stream>>>(rp + 2 * RP_STRIDE, sp2_c, sp2_v, o_embc, tmp2);
  gemm_dec_kernel<3000><<<dim3(gemm_grid), blk, 0, stream>>>(tmp1, dec1_w, o_rec1, N_NODES);
  gemm_dec_kernel<1000><<<dim3(gemm_grid), blk, 0, stream>>>(tmp2, dec2_w, o_rec2, N_NODES);
}